// Round 3
// baseline (103.924 us; speedup 1.0000x reference)
//
#include <hip/hip_runtime.h>
#include <math.h>

// Problem constants: R=4, I=16, N=2048.
#define RDIM 4
#define IDIM 16
#define NPAIR 64
#define NPTS 2048
#define THREADS 256
#define ROWSB 256                   // rows per block (64 per wave)
#define RBLK (NPTS / ROWSB)         // 8
#define TILES (NPTS / 32)           // 64 col-tiles of 32
#define SCRS 64                     // scratch row stride: [4][32][64] f32 = 32768 B -> LDS 40960 B = 4 blocks/CU
#define PSPLIT 4                    // prep parallelism split
#define ONEBF 0x3F80u               // bf16(1.0)

typedef __attribute__((ext_vector_type(8))) short bf16x8;
typedef __attribute__((ext_vector_type(16))) float f32x16;
typedef __attribute__((ext_vector_type(4))) float f32x4;

// fminf chain -> backend fuses to v_min3_f32 (minnum ISel pattern); no inline asm.
__device__ __forceinline__ float min3f(float a, float b, float c) {
    return fminf(a, fminf(b, c));
}

__device__ __forceinline__ unsigned int f2bf(float f) {
    union { float f; unsigned int u; } v; v.f = f;
    return (v.u + 0x7FFFu + ((v.u >> 16) & 1u)) >> 16;   // RNE bf16 (low 16 bits)
}
__device__ __forceinline__ float bf2f(unsigned int h) {
    union { unsigned int u; float f; } v; v.u = h << 16; return v.f;
}

__device__ __forceinline__ void make_rot(const float* __restrict__ rotv, int pair,
                                         float& r00, float& r01, float& r02,
                                         float& r10, float& r11, float& r12,
                                         float& r20, float& r21, float& r22) {
    const float ax = rotv[pair * 3 + 0];
    const float ay = rotv[pair * 3 + 1];
    const float az = rotv[pair * 3 + 2];
    float sx, cx, sy, cy, sz, cz;
    sincosf(ax, &sx, &cx);
    sincosf(ay, &sy, &cy);
    sincosf(az, &sz, &cz);
    r00 = cy * cz;                r01 = -cy * sz;               r02 = sy;
    r10 = cx * sz + sx * sy * cz; r11 = cx * cz - sx * sy * sz; r12 = -sx * cy;
    r20 = sx * sz - cx * sy * cz; r21 = sx * cz + cx * sy * sz; r22 = cx * cy;
}

// B-record (16 B, same content read by both k-halves):
//   shorts [bh0,bh1,bh2, bl0,bl1,bl2, n2h, n2l],  b = split(-2v), n2 = |v|^2
__device__ __forceinline__ uint4 brec(float v0, float v1, float v2) {
    const float b0 = -2.0f * v0, b1 = -2.0f * v1, b2 = -2.0f * v2;
    const unsigned int h0 = f2bf(b0), h1 = f2bf(b1), h2 = f2bf(b2);
    const unsigned int l0 = f2bf(b0 - bf2f(h0));
    const unsigned int l1 = f2bf(b1 - bf2f(h1));
    const unsigned int l2 = f2bf(b2 - bf2f(h2));
    const float n2 = v0 * v0 + v1 * v1 + v2 * v2;
    const unsigned int nh = f2bf(n2), nl = f2bf(n2 - bf2f(nh));
    return make_uint4(h0 | (h1 << 16), h2 | (l0 << 16), l1 | (l2 << 16), nh | (nl << 16));
}
// A-record (32 B): half0 = [qh0,qh1,qh2, ql0,ql1,ql2, 1, 0]
//                  half1 = [ql0,ql1,ql2, qh0,qh1,qh2, 0, 1]
// D = (qh+ql).(bh+bl) + 1*n2h + 1*n2l = -2 q.v + |v|^2   (exact to ~1e-5)
__device__ __forceinline__ void arec(float q0, float q1, float q2, uint4& a0, uint4& a1) {
    const unsigned int h0 = f2bf(q0), h1 = f2bf(q1), h2 = f2bf(q2);
    const unsigned int l0 = f2bf(q0 - bf2f(h0));
    const unsigned int l1 = f2bf(q1 - bf2f(h1));
    const unsigned int l2 = f2bf(q2 - bf2f(h2));
    a0 = make_uint4(h0 | (h1 << 16), h2 | (l0 << 16), l1 | (l2 << 16), ONEBF);
    a1 = make_uint4(l0 | (l1 << 16), l2 | (h0 << 16), h1 | (h2 << 16), ONEBF << 16);
}

// K0: build A/B records for both point sets. Grid (80, PSPLIT).
//   x-blocks 0..63: transformed source (per pair) -> Yb, Ya
//   x-blocks 64..79: target (per i)               -> Xb, Xa
__global__ __launch_bounds__(THREADS)
void prep(const float* __restrict__ src, const float* __restrict__ tgt,
          const float* __restrict__ rotv, const float* __restrict__ trav,
          const float* __restrict__ scal,
          uint4* __restrict__ Yb, uint4* __restrict__ Ya,
          uint4* __restrict__ Xb, uint4* __restrict__ Xa)
{
    const int b   = blockIdx.x;
    const int seg = blockIdx.y;
    const int tid = threadIdx.x;
    const int m0  = seg * (NPTS / PSPLIT);
    if (b < NPAIR) {
        const int pair = b;
        float r00, r01, r02, r10, r11, r12, r20, r21, r22;
        make_rot(rotv, pair, r00, r01, r02, r10, r11, r12, r20, r21, r22);
        const float t0 = trav[pair * 3 + 0];
        const float t1 = trav[pair * 3 + 1];
        const float t2 = trav[pair * 3 + 2];
        const float s  = scal[pair];
        const float* __restrict__ srcp = src + (size_t)pair * NPTS * 3;
#pragma unroll
        for (int u = 0; u < NPTS / THREADS / PSPLIT; ++u) {
            const int m = m0 + u * THREADS + tid;
            const float p0 = srcp[m * 3 + 0];
            const float p1 = srcp[m * 3 + 1];
            const float p2 = srcp[m * 3 + 2];
            const float y0 = s * fmaf(r00, p0, fmaf(r01, p1, fmaf(r02, p2, t0)));
            const float y1 = s * fmaf(r10, p0, fmaf(r11, p1, fmaf(r12, p2, t1)));
            const float y2 = s * fmaf(r20, p0, fmaf(r21, p1, fmaf(r22, p2, t2)));
            Yb[(size_t)pair * NPTS + m] = brec(y0, y1, y2);
            uint4 a0, a1;
            arec(y0, y1, y2, a0, a1);
            Ya[((size_t)pair * NPTS + m) * 2 + 0] = a0;
            Ya[((size_t)pair * NPTS + m) * 2 + 1] = a1;
        }
    } else {
        const int i = b - NPAIR;
        const float* __restrict__ tgtp = tgt + (size_t)i * NPTS * 3;
#pragma unroll
        for (int u = 0; u < NPTS / THREADS / PSPLIT; ++u) {
            const int m = m0 + u * THREADS + tid;
            const float x0 = tgtp[m * 3 + 0];
            const float x1 = tgtp[m * 3 + 1];
            const float x2 = tgtp[m * 3 + 2];
            Xb[(size_t)i * NPTS + m] = brec(x0, x1, x2);
            uint4 a0, a1;
            arec(x0, x1, x2, a0, a1);
            Xa[((size_t)i * NPTS + m) * 2 + 0] = a0;
            Xa[((size_t)i * NPTS + m) * 2 + 1] = a1;
        }
    }
}

// K1: per (pair, rowblock, pass). Each wave owns 64 rows x all 2048 cols.
// 32x32x16 MFMA, paired col-tiles (min3-fusable fmin chains), LDS-transpose endgame.
// LDS = 32768 (sB/scratch overlay) + 8192 (sA) = 40960 B -> exactly 4 blocks/CU.
__global__ __launch_bounds__(THREADS, 4)
void chamfer_main(const uint4* __restrict__ Yb, const uint4* __restrict__ Ya,
                  const uint4* __restrict__ Xb, const uint4* __restrict__ Xa,
                  float* __restrict__ out)
{
    // smem layout: [0, 32768): sB (32 KB, loop) / scratch (32 KB, endgame overlay)
    //              [32768, 40960): sA (8 KB, survives both phases)
    __shared__ alignas(16) unsigned char smem[32768 + 8192];
    __shared__ float wsum[4];
    unsigned short* sB = (unsigned short*)smem;           // [2048][8] shorts
    float* scratch = (float*)smem;                        // [4][32][SCRS]
    unsigned short* sA = (unsigned short*)(smem + 32768); // [256][16] shorts

    const int pair  = blockIdx.x;
    const int rb    = blockIdx.y;
    const int passB = blockIdx.z;  // 0: rows=target, cols=transformed; 1: swapped
    const int i     = pair & (IDIM - 1);
    const int tid   = threadIdx.x;
    const int lane  = tid & 63;
    const int w     = tid >> 6;
    const int c31   = lane & 31;
    const int h     = lane >> 5;

    const uint4* __restrict__ gB = (passB == 0) ? (Yb + (size_t)pair * NPTS)
                                                : (Xb + (size_t)i * NPTS);
    const uint4* __restrict__ gA = (passB == 0)
        ? (Xa + ((size_t)i * NPTS + rb * ROWSB) * 2)
        : (Ya + ((size_t)pair * NPTS + rb * ROWSB) * 2);

    // ---- stage: sB 2048x16B (8 uint4/thread), sA 256x32B (2 uint4/thread) ----
#pragma unroll
    for (int j = 0; j < 8; ++j)
        ((uint4*)sB)[j * THREADS + tid] = gB[j * THREADS + tid];
    ((uint4*)sA)[tid] = gA[tid];
    ((uint4*)sA)[THREADS + tid] = gA[THREADS + tid];
    __syncthreads();

    // ---- A fragments: wave w's rows [w*64, w*64+64), 2 row-tiles of 32 ----
    bf16x8 af[2];
    af[0] = *(const bf16x8*)&sA[(w * 64 + c31) * 16 + h * 8];
    af[1] = *(const bf16x8*)&sA[(w * 64 + 32 + c31) * 16 + h * 8];

    float mn[2][16];
#pragma unroll
    for (int rt = 0; rt < 2; ++rt)
#pragma unroll
        for (int j = 0; j < 16; ++j) mn[rt][j] = 3.4e38f;

    const f32x16 zero16 = {0,0,0,0, 0,0,0,0, 0,0,0,0, 0,0,0,0};

    // ---- main loop: 64 col-tiles in pairs; fmin chain fuses to v_min3 (2 evals/instr) ----
#pragma unroll 2
    for (int t = 0; t < TILES; t += 2) {
        const bf16x8 bfA = *(const bf16x8*)&sB[((t + 0) * 32 + c31) * 8];
        const bf16x8 bfB = *(const bf16x8*)&sB[((t + 1) * 32 + c31) * 8];
        const f32x16 a0 = __builtin_amdgcn_mfma_f32_32x32x16_bf16(af[0], bfA, zero16, 0, 0, 0);
        const f32x16 b0 = __builtin_amdgcn_mfma_f32_32x32x16_bf16(af[0], bfB, zero16, 0, 0, 0);
#pragma unroll
        for (int j = 0; j < 16; ++j)
            mn[0][j] = min3f(mn[0][j], a0[j], b0[j]);
        const f32x16 a1 = __builtin_amdgcn_mfma_f32_32x32x16_bf16(af[1], bfA, zero16, 0, 0, 0);
        const f32x16 b1 = __builtin_amdgcn_mfma_f32_32x32x16_bf16(af[1], bfB, zero16, 0, 0, 0);
#pragma unroll
        for (int j = 0; j < 16; ++j)
            mn[1][j] = min3f(mn[1][j], a1[j], b1[j]);
    }
    __syncthreads();   // done with sB; scratch overlays it

    // ---- endgame: LDS transpose. acc reg j of tile rt -> local row rt*32+8*(j>>2)+4*h+(j&3)
    // slot(class, row) = scratch[w][class][row ^ ((class&7)<<2)]
    //   XOR swizzle (bits 2..4, keeps 16B groups) breaks the SCRS=64 32-way write conflict;
    //   reads (fixed class, lane-varying row) stay conflict-free.
#pragma unroll
    for (int rt = 0; rt < 2; ++rt)
#pragma unroll
        for (int g2 = 0; g2 < 4; ++g2) {
            const int rowb = (rt * 32 + 8 * g2 + 4 * h) ^ ((c31 & 7) << 2);
            f32x4 v4;
            v4[0] = mn[rt][g2 * 4 + 0];
            v4[1] = mn[rt][g2 * 4 + 1];
            v4[2] = mn[rt][g2 * 4 + 2];
            v4[3] = mn[rt][g2 * 4 + 3];
            *(f32x4*)&scratch[(w * 32 + c31) * SCRS + rowb] = v4;
        }
    __syncthreads();

    // ---- thread t = block-row t: min across col-classes 0..31, add |q|^2 ----
    // Seed with classes 0 and 31, then 15 min3 pairs over classes 1..30 (16 ops).
    float m = fminf(scratch[(w * 32 + 0) * SCRS + lane],
                    scratch[(w * 32 + 31) * SCRS + (lane ^ ((31 & 7) << 2))]);
#pragma unroll
    for (int c = 1; c < 31; c += 2)
        m = min3f(m, scratch[(w * 32 + c) * SCRS + (lane ^ ((c & 7) << 2))],
                     scratch[(w * 32 + c + 1) * SCRS + (lane ^ (((c + 1) & 7) << 2))]);

    const unsigned short* ar = &sA[tid * 16];   // half0: [qh0,qh1,qh2, ql0,ql1,ql2, ...]
    const float q0 = bf2f(ar[0]) + bf2f(ar[3]);
    const float q1 = bf2f(ar[1]) + bf2f(ar[4]);
    const float q2 = bf2f(ar[2]) + bf2f(ar[5]);
    float v = m + q0 * q0 + q1 * q1 + q2 * q2;

#pragma unroll
    for (int off = 32; off > 0; off >>= 1)
        v += __shfl_down(v, off, 64);
    if (lane == 0) wsum[w] = v;
    __syncthreads();
    if (tid == 0) {
        const float tot = wsum[0] + wsum[1] + wsum[2] + wsum[3];
        atomicAdd(&out[pair], tot * (1.0f / NPTS));
    }
}

extern "C" void kernel_launch(void* const* d_in, const int* in_sizes, int n_in,
                              void* d_out, int out_size, void* d_ws, size_t ws_size,
                              hipStream_t stream) {
    const float* src  = (const float*)d_in[0];  // [4,16,2048,3]
    const float* tgt  = (const float*)d_in[1];  // [16,2048,3]
    const float* rotv = (const float*)d_in[2];  // [4,16,3]
    const float* trav = (const float*)d_in[3];  // [4,16,3]
    const float* scal = (const float*)d_in[4];  // [4,16]
    float* out = (float*)d_out;                 // [4,16]

    // ws: Yb 2 MB | Ya 4 MB | Xb 0.5 MB | Xa 1 MB  = 7.5 MB
    char* ws = (char*)d_ws;
    uint4* Yb = (uint4*)ws;
    uint4* Ya = (uint4*)(ws + (size_t)NPAIR * NPTS * 16);
    uint4* Xb = (uint4*)(ws + (size_t)NPAIR * NPTS * 48);
    uint4* Xa = (uint4*)(ws + (size_t)NPAIR * NPTS * 48 + (size_t)IDIM * NPTS * 16);

    hipMemsetAsync(out, 0, NPAIR * sizeof(float), stream);

    dim3 pgrid(NPAIR + IDIM, PSPLIT);
    prep<<<pgrid, THREADS, 0, stream>>>(src, tgt, rotv, trav, scal, Yb, Ya, Xb, Xa);

    dim3 grid(NPAIR, RBLK, 2);
    chamfer_main<<<grid, THREADS, 0, stream>>>(Yb, Ya, Xb, Xa, out);
}

// Round 4
// 100.241 us; speedup vs baseline: 1.0367x; 1.0367x over previous
//
#include <hip/hip_runtime.h>
#include <math.h>

// Problem constants: R=4, I=16, N=2048.
#define RDIM 4
#define IDIM 16
#define NPAIR 64
#define NPTS 2048
#define THREADS 256
#define ROWSB 256                   // rows per block (64 per wave)
#define RBLK (NPTS / ROWSB)         // 8
#define TILES (NPTS / 32)           // 64 col-tiles of 32
#define SCRS 64                     // scratch row stride (floats); XOR swizzle handles conflicts
#define PSPLIT 4                    // prep parallelism split
#define ONEBF 0x3F80u               // bf16(1.0)

typedef __attribute__((ext_vector_type(8))) short bf16x8;
typedef __attribute__((ext_vector_type(16))) float f32x16;
typedef __attribute__((ext_vector_type(4))) float f32x4;

// fminf chain -> backend can fuse to v_min3_f32; no inline asm.
__device__ __forceinline__ float min3f(float a, float b, float c) {
    return fminf(a, fminf(b, c));
}

__device__ __forceinline__ unsigned int f2bf(float f) {
    union { float f; unsigned int u; } v; v.f = f;
    return (v.u + 0x7FFFu + ((v.u >> 16) & 1u)) >> 16;   // RNE bf16 (low 16 bits)
}
__device__ __forceinline__ float bf2f(unsigned int h) {
    union { unsigned int u; float f; } v; v.u = h << 16; return v.f;
}

__device__ __forceinline__ void make_rot(const float* __restrict__ rotv, int pair,
                                         float& r00, float& r01, float& r02,
                                         float& r10, float& r11, float& r12,
                                         float& r20, float& r21, float& r22) {
    const float ax = rotv[pair * 3 + 0];
    const float ay = rotv[pair * 3 + 1];
    const float az = rotv[pair * 3 + 2];
    float sx, cx, sy, cy, sz, cz;
    sincosf(ax, &sx, &cx);
    sincosf(ay, &sy, &cy);
    sincosf(az, &sz, &cz);
    r00 = cy * cz;                r01 = -cy * sz;               r02 = sy;
    r10 = cx * sz + sx * sy * cz; r11 = cx * cz - sx * sy * sz; r12 = -sx * cy;
    r20 = sx * sz - cx * sy * cz; r21 = sx * cz + cx * sy * sz; r22 = cx * cy;
}

// B-record (16 B, same content read by both k-halves):
//   shorts [bh0,bh1,bh2, bl0,bl1,bl2, n2h, n2l],  b = split(-2v), n2 = |v|^2
__device__ __forceinline__ uint4 brec(float v0, float v1, float v2) {
    const float b0 = -2.0f * v0, b1 = -2.0f * v1, b2 = -2.0f * v2;
    const unsigned int h0 = f2bf(b0), h1 = f2bf(b1), h2 = f2bf(b2);
    const unsigned int l0 = f2bf(b0 - bf2f(h0));
    const unsigned int l1 = f2bf(b1 - bf2f(h1));
    const unsigned int l2 = f2bf(b2 - bf2f(h2));
    const float n2 = v0 * v0 + v1 * v1 + v2 * v2;
    const unsigned int nh = f2bf(n2), nl = f2bf(n2 - bf2f(nh));
    return make_uint4(h0 | (h1 << 16), h2 | (l0 << 16), l1 | (l2 << 16), nh | (nl << 16));
}
// A-record (32 B): half0 = [qh0,qh1,qh2, ql0,ql1,ql2, 1, 0]
//                  half1 = [ql0,ql1,ql2, qh0,qh1,qh2, 0, 1]
// D = (qh+ql).(bh+bl) + 1*n2h + 1*n2l = -2 q.v + |v|^2   (exact to ~1e-5)
__device__ __forceinline__ void arec(float q0, float q1, float q2, uint4& a0, uint4& a1) {
    const unsigned int h0 = f2bf(q0), h1 = f2bf(q1), h2 = f2bf(q2);
    const unsigned int l0 = f2bf(q0 - bf2f(h0));
    const unsigned int l1 = f2bf(q1 - bf2f(h1));
    const unsigned int l2 = f2bf(q2 - bf2f(h2));
    a0 = make_uint4(h0 | (h1 << 16), h2 | (l0 << 16), l1 | (l2 << 16), ONEBF);
    a1 = make_uint4(l0 | (l1 << 16), l2 | (h0 << 16), h1 | (h2 << 16), ONEBF << 16);
}

// K0: build A/B records for both point sets. Grid (80, PSPLIT).
//   x-blocks 0..63: transformed source (per pair) -> Yb, Ya
//   x-blocks 64..79: target (per i)               -> Xb, Xa
__global__ __launch_bounds__(THREADS)
void prep(const float* __restrict__ src, const float* __restrict__ tgt,
          const float* __restrict__ rotv, const float* __restrict__ trav,
          const float* __restrict__ scal,
          uint4* __restrict__ Yb, uint4* __restrict__ Ya,
          uint4* __restrict__ Xb, uint4* __restrict__ Xa)
{
    const int b   = blockIdx.x;
    const int seg = blockIdx.y;
    const int tid = threadIdx.x;
    const int m0  = seg * (NPTS / PSPLIT);
    if (b < NPAIR) {
        const int pair = b;
        float r00, r01, r02, r10, r11, r12, r20, r21, r22;
        make_rot(rotv, pair, r00, r01, r02, r10, r11, r12, r20, r21, r22);
        const float t0 = trav[pair * 3 + 0];
        const float t1 = trav[pair * 3 + 1];
        const float t2 = trav[pair * 3 + 2];
        const float s  = scal[pair];
        const float* __restrict__ srcp = src + (size_t)pair * NPTS * 3;
#pragma unroll
        for (int u = 0; u < NPTS / THREADS / PSPLIT; ++u) {
            const int m = m0 + u * THREADS + tid;
            const float p0 = srcp[m * 3 + 0];
            const float p1 = srcp[m * 3 + 1];
            const float p2 = srcp[m * 3 + 2];
            const float y0 = s * fmaf(r00, p0, fmaf(r01, p1, fmaf(r02, p2, t0)));
            const float y1 = s * fmaf(r10, p0, fmaf(r11, p1, fmaf(r12, p2, t1)));
            const float y2 = s * fmaf(r20, p0, fmaf(r21, p1, fmaf(r22, p2, t2)));
            Yb[(size_t)pair * NPTS + m] = brec(y0, y1, y2);
            uint4 a0, a1;
            arec(y0, y1, y2, a0, a1);
            Ya[((size_t)pair * NPTS + m) * 2 + 0] = a0;
            Ya[((size_t)pair * NPTS + m) * 2 + 1] = a1;
        }
    } else {
        const int i = b - NPAIR;
        const float* __restrict__ tgtp = tgt + (size_t)i * NPTS * 3;
#pragma unroll
        for (int u = 0; u < NPTS / THREADS / PSPLIT; ++u) {
            const int m = m0 + u * THREADS + tid;
            const float x0 = tgtp[m * 3 + 0];
            const float x1 = tgtp[m * 3 + 1];
            const float x2 = tgtp[m * 3 + 2];
            Xb[(size_t)i * NPTS + m] = brec(x0, x1, x2);
            uint4 a0, a1;
            arec(x0, x1, x2, a0, a1);
            Xa[((size_t)i * NPTS + m) * 2 + 0] = a0;
            Xa[((size_t)i * NPTS + m) * 2 + 1] = a1;
        }
    }
}

// K1: per (pair, rowblock, pass). Each wave owns 64 rows x all 2048 cols.
// 32x32x16 MFMA with a runtime-opaque zero C-operand (czero kernel arg): the
// compiler must keep one resident 16-reg C vector in VGPRs instead of
// re-materializing zeros / bouncing accumulators through AGPRs per MFMA.
// __launch_bounds__(256,3): ~170-reg cap -> accumulators stay in arch VGPRs.
__global__ __launch_bounds__(THREADS, 3)
void chamfer_main(const uint4* __restrict__ Yb, const uint4* __restrict__ Ya,
                  const uint4* __restrict__ Xb, const uint4* __restrict__ Xa,
                  float* __restrict__ out, const float czero)
{
    // smem layout: [0, 32768): sB (32 KB, loop) / scratch (32 KB, endgame overlay)
    //              [32768, 40960): sA (8 KB, survives both phases)
    __shared__ alignas(16) unsigned char smem[32768 + 8192];
    __shared__ float wsum[4];
    unsigned short* sB = (unsigned short*)smem;           // [2048][8] shorts
    float* scratch = (float*)smem;                        // [4][32][SCRS]
    unsigned short* sA = (unsigned short*)(smem + 32768); // [256][16] shorts

    const int pair  = blockIdx.x;
    const int rb    = blockIdx.y;
    const int passB = blockIdx.z;  // 0: rows=target, cols=transformed; 1: swapped
    const int i     = pair & (IDIM - 1);
    const int tid   = threadIdx.x;
    const int lane  = tid & 63;
    const int w     = tid >> 6;
    const int c31   = lane & 31;
    const int h     = lane >> 5;

    const uint4* __restrict__ gB = (passB == 0) ? (Yb + (size_t)pair * NPTS)
                                                : (Xb + (size_t)i * NPTS);
    const uint4* __restrict__ gA = (passB == 0)
        ? (Xa + ((size_t)i * NPTS + rb * ROWSB) * 2)
        : (Ya + ((size_t)pair * NPTS + rb * ROWSB) * 2);

    // ---- stage: sB 2048x16B (8 uint4/thread), sA 256x32B (2 uint4/thread) ----
#pragma unroll
    for (int j = 0; j < 8; ++j)
        ((uint4*)sB)[j * THREADS + tid] = gB[j * THREADS + tid];
    ((uint4*)sA)[tid] = gA[tid];
    ((uint4*)sA)[THREADS + tid] = gA[THREADS + tid];
    __syncthreads();

    // ---- A fragments: wave w's rows [w*64, w*64+64), 2 row-tiles of 32 ----
    bf16x8 af[2];
    af[0] = *(const bf16x8*)&sA[(w * 64 + c31) * 16 + h * 8];
    af[1] = *(const bf16x8*)&sA[(w * 64 + 32 + c31) * 16 + h * 8];

    float mn[2][16];
#pragma unroll
    for (int rt = 0; rt < 2; ++rt)
#pragma unroll
        for (int j = 0; j < 16; ++j) mn[rt][j] = 3.4e38f;

    // Runtime-opaque zeros: built from the czero kernel argument, so the
    // compiler cannot const-fold or re-materialize; stays resident as C.
    f32x16 zero16;
#pragma unroll
    for (int j = 0; j < 16; ++j) zero16[j] = czero;

    // ---- main loop: 64 col-tiles in pairs; fmin chain fuses to v_min3 (2 evals/instr) ----
#pragma unroll 2
    for (int t = 0; t < TILES; t += 2) {
        const bf16x8 bfA = *(const bf16x8*)&sB[((t + 0) * 32 + c31) * 8];
        const bf16x8 bfB = *(const bf16x8*)&sB[((t + 1) * 32 + c31) * 8];
        const f32x16 a0 = __builtin_amdgcn_mfma_f32_32x32x16_bf16(af[0], bfA, zero16, 0, 0, 0);
        const f32x16 b0 = __builtin_amdgcn_mfma_f32_32x32x16_bf16(af[0], bfB, zero16, 0, 0, 0);
#pragma unroll
        for (int j = 0; j < 16; ++j)
            mn[0][j] = min3f(mn[0][j], a0[j], b0[j]);
        const f32x16 a1 = __builtin_amdgcn_mfma_f32_32x32x16_bf16(af[1], bfA, zero16, 0, 0, 0);
        const f32x16 b1 = __builtin_amdgcn_mfma_f32_32x32x16_bf16(af[1], bfB, zero16, 0, 0, 0);
#pragma unroll
        for (int j = 0; j < 16; ++j)
            mn[1][j] = min3f(mn[1][j], a1[j], b1[j]);
    }
    __syncthreads();   // done with sB; scratch overlays it

    // ---- endgame: LDS transpose. acc reg j of tile rt -> local row rt*32+8*(j>>2)+4*h+(j&3)
    // slot(class, row) = scratch[w][class][row ^ ((class&7)<<2)]
    //   XOR swizzle (bits 2..4, keeps 16B groups) breaks the SCRS=64 32-way write conflict;
    //   reads (fixed class, lane-varying row) stay conflict-free.
#pragma unroll
    for (int rt = 0; rt < 2; ++rt)
#pragma unroll
        for (int g2 = 0; g2 < 4; ++g2) {
            const int rowb = (rt * 32 + 8 * g2 + 4 * h) ^ ((c31 & 7) << 2);
            f32x4 v4;
            v4[0] = mn[rt][g2 * 4 + 0];
            v4[1] = mn[rt][g2 * 4 + 1];
            v4[2] = mn[rt][g2 * 4 + 2];
            v4[3] = mn[rt][g2 * 4 + 3];
            *(f32x4*)&scratch[(w * 32 + c31) * SCRS + rowb] = v4;
        }
    __syncthreads();

    // ---- thread t = block-row t: min across col-classes 0..31, add |q|^2 ----
    // Seed with classes 0 and 31, then 15 min3 pairs over classes 1..30 (16 ops).
    float m = fminf(scratch[(w * 32 + 0) * SCRS + lane],
                    scratch[(w * 32 + 31) * SCRS + (lane ^ ((31 & 7) << 2))]);
#pragma unroll
    for (int c = 1; c < 31; c += 2)
        m = min3f(m, scratch[(w * 32 + c) * SCRS + (lane ^ ((c & 7) << 2))],
                     scratch[(w * 32 + c + 1) * SCRS + (lane ^ (((c + 1) & 7) << 2))]);

    const unsigned short* ar = &sA[tid * 16];   // half0: [qh0,qh1,qh2, ql0,ql1,ql2, ...]
    const float q0 = bf2f(ar[0]) + bf2f(ar[3]);
    const float q1 = bf2f(ar[1]) + bf2f(ar[4]);
    const float q2 = bf2f(ar[2]) + bf2f(ar[5]);
    float v = m + q0 * q0 + q1 * q1 + q2 * q2;

#pragma unroll
    for (int off = 32; off > 0; off >>= 1)
        v += __shfl_down(v, off, 64);
    if (lane == 0) wsum[w] = v;
    __syncthreads();
    if (tid == 0) {
        const float tot = wsum[0] + wsum[1] + wsum[2] + wsum[3];
        atomicAdd(&out[pair], tot * (1.0f / NPTS));
    }
}

extern "C" void kernel_launch(void* const* d_in, const int* in_sizes, int n_in,
                              void* d_out, int out_size, void* d_ws, size_t ws_size,
                              hipStream_t stream) {
    const float* src  = (const float*)d_in[0];  // [4,16,2048,3]
    const float* tgt  = (const float*)d_in[1];  // [16,2048,3]
    const float* rotv = (const float*)d_in[2];  // [4,16,3]
    const float* trav = (const float*)d_in[3];  // [4,16,3]
    const float* scal = (const float*)d_in[4];  // [4,16]
    float* out = (float*)d_out;                 // [4,16]

    // ws: Yb 2 MB | Ya 4 MB | Xb 0.5 MB | Xa 1 MB  = 7.5 MB
    char* ws = (char*)d_ws;
    uint4* Yb = (uint4*)ws;
    uint4* Ya = (uint4*)(ws + (size_t)NPAIR * NPTS * 16);
    uint4* Xb = (uint4*)(ws + (size_t)NPAIR * NPTS * 48);
    uint4* Xa = (uint4*)(ws + (size_t)NPAIR * NPTS * 48 + (size_t)IDIM * NPTS * 16);

    hipMemsetAsync(out, 0, NPAIR * sizeof(float), stream);

    dim3 pgrid(NPAIR + IDIM, PSPLIT);
    prep<<<pgrid, THREADS, 0, stream>>>(src, tgt, rotv, trav, scal, Yb, Ya, Xb, Xa);

    dim3 grid(NPAIR, RBLK, 2);
    chamfer_main<<<grid, THREADS, 0, stream>>>(Yb, Ya, Xb, Xa, out, 0.0f);
}